// Round 4
// baseline (304.671 us; speedup 1.0000x reference)
//
#include <hip/hip_runtime.h>
#include <hip/hip_bf16.h>

static constexpr int M_TOT = 8192;   // 4 * 2048
static constexpr int N_TOT = 4096;   // OUT_F
static constexpr int K_TOT = 4096;   // IN_F

static constexpr int BM = 256, BN = 256, BK = 32;
static constexpr int NT = K_TOT / BK;        // 128 K-tiles
static constexpr int GTHREADS = 512;         // 8 waves (2 M x 4 N)
static constexpr int BUF_BYTES = 32768;      // A 16K + B 16K per K-tile buffer
static constexpr int LDS_BYTES = 4 * BUF_BYTES;  // ring-4 = 128 KiB

typedef __bf16 bf16x8 __attribute__((ext_vector_type(8)));
typedef float f32x16 __attribute__((ext_vector_type(16)));
typedef unsigned short u16x8 __attribute__((ext_vector_type(8)));

__device__ __forceinline__ unsigned short f2bf(float f) {
  return __builtin_bit_cast(unsigned short, (__bf16)f);
}

// FP4 E2M1 decode: mag 0..7 -> 0,0.5,1,1.5,2,3,4,6 ; bit 3 = sign
__device__ __forceinline__ float fp4_decode(int idx) {
  unsigned u = (unsigned)idx & 15u;
  unsigned sgn = (u >> 3) << 31;
  unsigned mag = u & 7u;
  unsigned e = mag >> 1, m = mag & 1u;
  unsigned bits = (e == 0u) ? (m ? 0x3F000000u : 0u)
                            : (((126u + e) << 23) | (m << 22));
  return __uint_as_float(bits | sgn);
}

__device__ __forceinline__ void glds16(const void* g, void* l) {
  __builtin_amdgcn_global_load_lds(
      (__attribute__((address_space(1))) void*)g,
      (__attribute__((address_space(3))) void*)l, 16, 0, 0);
}

// ---- prepass: weights int32 idx + scales -> bf16 W [N][K] -------------------
__global__ __launch_bounds__(256) void dequant_w_kernel(
    const int* __restrict__ idx, const float* __restrict__ scales,
    unsigned short* __restrict__ W) {
  const int t = blockIdx.x * 256 + threadIdx.x;  // 4 indices per thread
  const int4 v = reinterpret_cast<const int4*>(idx)[t];
  const float s = scales[t >> 2];
  ushort4 o;
  o.x = f2bf(fp4_decode(v.x) * s);
  o.y = f2bf(fp4_decode(v.y) * s);
  o.z = f2bf(fp4_decode(v.z) * s);
  o.w = f2bf(fp4_decode(v.w) * s);
  reinterpret_cast<ushort4*>(W)[t] = o;
}

// ---- prepass: x fp32 -> bf16 A [M][K] ---------------------------------------
__global__ __launch_bounds__(256) void convert_x_kernel(
    const float* __restrict__ x, unsigned short* __restrict__ A) {
  const int t = blockIdx.x * 256 + threadIdx.x;  // 8 floats per thread
  const float4* xp = reinterpret_cast<const float4*>(x);
  const float4 a = xp[2 * t], b = xp[2 * t + 1];
  u16x8 o;
  o[0] = f2bf(a.x); o[1] = f2bf(a.y); o[2] = f2bf(a.z); o[3] = f2bf(a.w);
  o[4] = f2bf(b.x); o[5] = f2bf(b.y); o[6] = f2bf(b.z); o[7] = f2bf(b.w);
  reinterpret_cast<u16x8*>(A)[t] = o;
}

// ---- GEMM: 256x256, BK=32, 32x32x16 MFMA, ring-4 LDS, counted vmcnt --------
__global__ __launch_bounds__(GTHREADS, 1) void gemm256(
    const unsigned short* __restrict__ A, const unsigned short* __restrict__ B,
    const float* __restrict__ bias, float* __restrict__ out) {
  extern __shared__ char smem[];

  const int t = threadIdx.x;
  const int lane = t & 63, wid = t >> 6;
  const int wr = wid >> 2;          // 0..1 (M half, 128 rows)
  const int wc = wid & 3;           // 0..3 (N quarter, 64 cols)
  const int l31 = lane & 31;        // row/col within 32x32 fragment
  const int kh = lane >> 5;         // k-half selector (8 bf16 each)

  // T1: XCD swizzle (512 blocks, 8 XCDs)
  const int bid = blockIdx.x;
  const int bmi = (bid & 7) * 4 + ((bid >> 3) & 3);  // 0..31
  const int bni = bid >> 5;                          // 0..15
  const int bm0 = bmi * BM, bn0 = bni * BN;

  // staging: linear LDS dest; source k-chunk pre-swizzled with the involution
  // c' = c ^ ((row>>1)&3)  (rows are 64 B = 4 chunks of 16 B)
  const int row_s = t >> 2;                   // 0..127
  const int kcd = (t & 3) ^ ((t >> 3) & 3);   // pre-swizzled global k-chunk
  const unsigned short* gA = A + (size_t)(bm0 + row_s) * K_TOT + kcd * 8;
  const unsigned short* gB = B + (size_t)(bn0 + row_s) * K_TOT + kcd * 8;
  char* ldsA = smem + t * 16;
  char* ldsB = smem + 16384 + t * 16;

  // ds_read side: same involution. Fragment row = (base rows multiple of 32) + l31,
  // so (row>>1)&3 == (l31>>1)&3. Global chunk = ks*2 + kh.
  const int s_ = (l31 >> 1) & 3;
  const int c0 = ((0 | kh) ^ s_) * 16;   // ks=0 chunk byte offset
  const int c1 = ((2 | kh) ^ s_) * 16;   // ks=1 chunk byte offset
  const int a_row = (wr * 128 + l31) * 64;
  const int b_row = 16384 + (wc * 64 + l31) * 64;
  const int base_a0 = a_row + c0, base_a1 = a_row + c1;
  const int base_b0 = b_row + c0, base_b1 = b_row + c1;

  f32x16 acc[4][2];
#pragma unroll
  for (int i = 0; i < 4; ++i)
#pragma unroll
    for (int j = 0; j < 2; ++j)
#pragma unroll
      for (int r = 0; r < 16; ++r) acc[i][j][r] = 0.f;

  bf16x8 afA[4], afB[4], bfA[2], bfB[2];

#define STAGE_A(kt, bufi) do {                                          \
    const unsigned short* p_ = gA + (size_t)(kt) * BK;                  \
    glds16(p_, ldsA + (bufi) * BUF_BYTES);                              \
    glds16(p_ + (size_t)128 * K_TOT, ldsA + (bufi) * BUF_BYTES + 8192); \
  } while (0)
#define STAGE_B(kt, bufi) do {                                          \
    const unsigned short* p_ = gB + (size_t)(kt) * BK;                  \
    glds16(p_, ldsB + (bufi) * BUF_BYTES);                              \
    glds16(p_ + (size_t)128 * K_TOT, ldsB + (bufi) * BUF_BYTES + 8192); \
  } while (0)

#define READ_A(dst, bufi, ksb) do {                                     \
    const char* p_ = smem + (bufi) * BUF_BYTES + (ksb);                 \
    dst[0] = *(const bf16x8*)(p_);                                      \
    dst[1] = *(const bf16x8*)(p_ + 2048);                               \
    dst[2] = *(const bf16x8*)(p_ + 4096);                               \
    dst[3] = *(const bf16x8*)(p_ + 6144);                               \
  } while (0)
#define READ_B(dst, bufi, ksb) do {                                     \
    const char* p_ = smem + (bufi) * BUF_BYTES + (ksb);                 \
    dst[0] = *(const bf16x8*)(p_);                                      \
    dst[1] = *(const bf16x8*)(p_ + 2048);                               \
  } while (0)

#define MFMA8(afs, bfs) do {                                            \
    __builtin_amdgcn_s_setprio(1);                                      \
    _Pragma("unroll")                                                   \
    for (int m_ = 0; m_ < 4; ++m_)                                      \
      _Pragma("unroll")                                                 \
      for (int n_ = 0; n_ < 2; ++n_)                                    \
        acc[m_][n_] = __builtin_amdgcn_mfma_f32_32x32x16_bf16(          \
            afs[m_], bfs[n_], acc[m_][n_], 0, 0, 0);                    \
    __builtin_amdgcn_s_setprio(0);                                      \
  } while (0)

#define VM(n) asm volatile("s_waitcnt vmcnt(" #n ")" ::: "memory")
#define BAR __builtin_amdgcn_s_barrier()

  // Phase A of tile tt (buf rb): read ks1 frags of tt, stage A(tt+3),
  // MFMA ks0, vmcnt(6)+barrier => tile tt+1 landed GLOBALLY.
#define PH_A(tt, rb, sb) do {                  \
    READ_A(afB, rb, base_a1);                  \
    READ_B(bfB, rb, base_b1);                  \
    STAGE_A((tt) + 3, sb);                     \
    MFMA8(afA, bfA);                           \
    VM(6); BAR;                                \
  } while (0)
  // Phase B of tile tt: read-ahead ks0 frags of tile tt+1 (landed),
  // stage B(tt+3), MFMA ks1, barrier.
#define PH_B(tt, rbn, sb) do {                 \
    READ_A(afA, rbn, base_a0);                 \
    READ_B(bfA, rbn, base_b0);                 \
    STAGE_B((tt) + 3, sb);                     \
    MFMA8(afB, bfB);                           \
    BAR;                                       \
  } while (0)

  // ---- prologue: stage tiles 0,1,2 (order pinned for vmcnt accounting)
  STAGE_A(0, 0); STAGE_B(0, 0);
  asm volatile("" ::: "memory");
  STAGE_A(1, 1); STAGE_B(1, 1);
  asm volatile("" ::: "memory");
  STAGE_A(2, 2); STAGE_B(2, 2);
  VM(8);  // tile 0 landed (own); barrier makes it global
  BAR;
  READ_A(afA, 0, base_a0);
  READ_B(bfA, 0, base_b0);

  // ---- main loop: tiles 0..123, stages 3..126 (4-tile unroll, static bufs)
#pragma unroll 1
  for (int tt = 0; tt < NT - 4; tt += 4) {
    PH_A(tt + 0, 0, 3); PH_B(tt + 0, 1, 3);
    PH_A(tt + 1, 1, 0); PH_B(tt + 1, 2, 0);
    PH_A(tt + 2, 2, 1); PH_B(tt + 2, 3, 1);
    PH_A(tt + 3, 3, 2); PH_B(tt + 3, 0, 2);
  }

  // ---- tail: tiles 124..127, drain 6 -> 4 -> 0
  // tile 124 (buf0), stages tile 127 -> buf3
  READ_A(afB, 0, base_a1); READ_B(bfB, 0, base_b1);
  STAGE_A(127, 3); MFMA8(afA, bfA); VM(6); BAR;
  READ_A(afA, 1, base_a0); READ_B(bfA, 1, base_b0);
  STAGE_B(127, 3); MFMA8(afB, bfB); BAR;
  // tile 125 (buf1): outstanding A(127)+B(127)=4 => tile 126 landed
  READ_A(afB, 1, base_a1); READ_B(bfB, 1, base_b1);
  MFMA8(afA, bfA); VM(4); BAR;
  READ_A(afA, 2, base_a0); READ_B(bfA, 2, base_b0);
  MFMA8(afB, bfB); BAR;
  // tile 126 (buf2): drain all => tile 127 landed
  READ_A(afB, 2, base_a1); READ_B(bfB, 2, base_b1);
  MFMA8(afA, bfA); VM(0); BAR;
  READ_A(afA, 3, base_a0); READ_B(bfA, 3, base_b0);
  MFMA8(afB, bfB); BAR;
  // tile 127 (buf3)
  READ_A(afB, 3, base_a1); READ_B(bfB, 3, base_b1);
  MFMA8(afA, bfA);
  MFMA8(afB, bfB);

  // ---- epilogue: 32x32 C/D layout col = lane&31, row = (reg&3)+8*(reg>>2)+4*kh
  const int orow_b = bm0 + wr * 128 + 4 * kh;
  const int ocol_b = bn0 + wc * 64 + l31;
  float bj[2];
  bj[0] = bias[ocol_b];
  bj[1] = bias[ocol_b + 32];
#pragma unroll
  for (int mi = 0; mi < 4; ++mi)
#pragma unroll
    for (int ni = 0; ni < 2; ++ni)
#pragma unroll
      for (int r = 0; r < 16; ++r) {
        const int row = orow_b + mi * 32 + (r & 3) + 8 * (r >> 2);
        out[(size_t)row * N_TOT + ocol_b + ni * 32] = acc[mi][ni][r] + bj[ni];
      }
}

extern "C" void kernel_launch(void* const* d_in, const int* in_sizes, int n_in,
                              void* d_out, int out_size, void* d_ws, size_t ws_size,
                              hipStream_t stream) {
  const float* x = (const float*)d_in[0];
  const int* widx = (const int*)d_in[1];
  const float* wsc = (const float*)d_in[2];
  const float* bias = (const float*)d_in[3];
  float* out = (float*)d_out;

  unsigned short* Abf = (unsigned short*)d_ws;                       // 64 MiB
  unsigned short* Wbf = (unsigned short*)((char*)d_ws + (size_t)M_TOT * K_TOT * 2);  // 32 MiB

  convert_x_kernel<<<dim3((M_TOT * (size_t)K_TOT / 8) / 256), dim3(256), 0, stream>>>(x, Abf);
  dequant_w_kernel<<<dim3((N_TOT * (size_t)K_TOT / 4) / 256), dim3(256), 0, stream>>>(widx, wsc, Wbf);

  (void)hipFuncSetAttribute((const void*)gemm256,
                            hipFuncAttributeMaxDynamicSharedMemorySize, LDS_BYTES);
  gemm256<<<dim3((M_TOT / BM) * (N_TOT / BN)), dim3(GTHREADS), LDS_BYTES, stream>>>(
      Abf, Wbf, bias, out);
}

// Round 5
// 303.471 us; speedup vs baseline: 1.0040x; 1.0040x over previous
//
#include <hip/hip_runtime.h>
#include <hip/hip_bf16.h>

static constexpr int M_TOT = 8192;   // 4 * 2048
static constexpr int N_TOT = 4096;   // OUT_F
static constexpr int K_TOT = 4096;   // IN_F

static constexpr int BM = 256, BN = 256, BK = 32;
static constexpr int NT = K_TOT / BK;        // 128 K-tiles
static constexpr int GTHREADS = 512;         // 8 waves (2 M x 4 N)
static constexpr int BUF_BYTES = 32768;      // A 16K + B 16K per K-tile buffer
static constexpr int LDS_BYTES = 4 * BUF_BYTES;  // ring-4 = 128 KiB

typedef __bf16 bf16x8 __attribute__((ext_vector_type(8)));
typedef float f32x16 __attribute__((ext_vector_type(16)));
typedef unsigned short u16x8 __attribute__((ext_vector_type(8)));

__device__ __forceinline__ unsigned short f2bf(float f) {
  return __builtin_bit_cast(unsigned short, (__bf16)f);
}

// FP4 E2M1 decode: mag 0..7 -> 0,0.5,1,1.5,2,3,4,6 ; bit 3 = sign
__device__ __forceinline__ float fp4_decode(int idx) {
  unsigned u = (unsigned)idx & 15u;
  unsigned sgn = (u >> 3) << 31;
  unsigned mag = u & 7u;
  unsigned e = mag >> 1, m = mag & 1u;
  unsigned bits = (e == 0u) ? (m ? 0x3F000000u : 0u)
                            : (((126u + e) << 23) | (m << 22));
  return __uint_as_float(bits | sgn);
}

__device__ __forceinline__ void glds16(const void* g, void* l) {
  __builtin_amdgcn_global_load_lds(
      (__attribute__((address_space(1))) void*)g,
      (__attribute__((address_space(3))) void*)l, 16, 0, 0);
}

// ---- prepass: weights int32 idx + scales -> bf16 W [N][K] -------------------
__global__ __launch_bounds__(256) void dequant_w_kernel(
    const int* __restrict__ idx, const float* __restrict__ scales,
    unsigned short* __restrict__ W) {
  const int t = blockIdx.x * 256 + threadIdx.x;  // 4 indices per thread
  const int4 v = reinterpret_cast<const int4*>(idx)[t];
  const float s = scales[t >> 2];
  ushort4 o;
  o.x = f2bf(fp4_decode(v.x) * s);
  o.y = f2bf(fp4_decode(v.y) * s);
  o.z = f2bf(fp4_decode(v.z) * s);
  o.w = f2bf(fp4_decode(v.w) * s);
  reinterpret_cast<ushort4*>(W)[t] = o;
}

// ---- prepass: x fp32 -> bf16 A [M][K] ---------------------------------------
__global__ __launch_bounds__(256) void convert_x_kernel(
    const float* __restrict__ x, unsigned short* __restrict__ A) {
  const int t = blockIdx.x * 256 + threadIdx.x;  // 8 floats per thread
  const float4* xp = reinterpret_cast<const float4*>(x);
  const float4 a = xp[2 * t], b = xp[2 * t + 1];
  u16x8 o;
  o[0] = f2bf(a.x); o[1] = f2bf(a.y); o[2] = f2bf(a.z); o[3] = f2bf(a.w);
  o[4] = f2bf(b.x); o[5] = f2bf(b.y); o[6] = f2bf(b.z); o[7] = f2bf(b.w);
  reinterpret_cast<u16x8*>(A)[t] = o;
}

// ---- GEMM: 256x256, BK=32, 32x32x16 MFMA, ring-4 LDS, counted vmcnt --------
// Swizzle involution (R4 postmortem fix): stored chunk = global chunk ^ s(row),
// s(row) = ((row>>1)&1)<<1 | ((row>>2)&1). Guarantees all 8 bank-quads
// distinct in every 8-lane ds_read_b128 phase (both contiguous-8 and
// i/i+32-paired groupings).
__global__ __launch_bounds__(GTHREADS, 1) void gemm256(
    const unsigned short* __restrict__ A, const unsigned short* __restrict__ B,
    const float* __restrict__ bias, float* __restrict__ out) {
  extern __shared__ char smem[];

  const int t = threadIdx.x;
  const int lane = t & 63, wid = t >> 6;
  const int wr = wid >> 2;          // 0..1 (M half, 128 rows)
  const int wc = wid & 3;           // 0..3 (N quarter, 64 cols)
  const int l31 = lane & 31;        // row/col within 32x32 fragment
  const int kh = lane >> 5;         // k-half selector (8 bf16 each)

  // T1: XCD swizzle (512 blocks, 8 XCDs)
  const int bid = blockIdx.x;
  const int bmi = (bid & 7) * 4 + ((bid >> 3) & 3);  // 0..31
  const int bni = bid >> 5;                          // 0..15
  const int bm0 = bmi * BM, bn0 = bni * BN;

  // staging: linear LDS dest; source k-chunk pre-swizzled with s(row)
  const int row_s = t >> 2;                                    // 0..127
  const int s_st = (((t >> 3) & 1) << 1) | ((t >> 4) & 1);     // s(row_s)
  const int kcd = (t & 3) ^ s_st;                              // global k-chunk
  const unsigned short* gA = A + (size_t)(bm0 + row_s) * K_TOT + kcd * 8;
  const unsigned short* gB = B + (size_t)(bn0 + row_s) * K_TOT + kcd * 8;
  char* ldsA = smem + t * 16;
  char* ldsB = smem + 16384 + t * 16;

  // ds_read side: same involution; fragment row = base(mult of 32) + l31,
  // s depends on row bits 1..2 only -> s(row) == s(l31).
  const int s_ = (((l31 >> 1) & 1) << 1) | ((l31 >> 2) & 1);
  const int c0 = ((0 | kh) ^ s_) * 16;   // ks=0: global chunk kh
  const int c1 = ((2 | kh) ^ s_) * 16;   // ks=1: global chunk 2+kh
  const int a_row = (wr * 128 + l31) * 64;
  const int b_row = 16384 + (wc * 64 + l31) * 64;
  const int base_a0 = a_row + c0, base_a1 = a_row + c1;
  const int base_b0 = b_row + c0, base_b1 = b_row + c1;

  f32x16 acc[4][2];
#pragma unroll
  for (int i = 0; i < 4; ++i)
#pragma unroll
    for (int j = 0; j < 2; ++j)
#pragma unroll
      for (int r = 0; r < 16; ++r) acc[i][j][r] = 0.f;

  bf16x8 afA[4], afB[4], bfA[2], bfB[2];

#define STAGE_A(kt, bufi) do {                                          \
    const unsigned short* p_ = gA + (size_t)(kt) * BK;                  \
    glds16(p_, ldsA + (bufi) * BUF_BYTES);                              \
    glds16(p_ + (size_t)128 * K_TOT, ldsA + (bufi) * BUF_BYTES + 8192); \
  } while (0)
#define STAGE_B(kt, bufi) do {                                          \
    const unsigned short* p_ = gB + (size_t)(kt) * BK;                  \
    glds16(p_, ldsB + (bufi) * BUF_BYTES);                              \
    glds16(p_ + (size_t)128 * K_TOT, ldsB + (bufi) * BUF_BYTES + 8192); \
  } while (0)

#define READ_A(dst, bufi, ksb) do {                                     \
    const char* p_ = smem + (bufi) * BUF_BYTES + (ksb);                 \
    dst[0] = *(const bf16x8*)(p_);                                      \
    dst[1] = *(const bf16x8*)(p_ + 2048);                               \
    dst[2] = *(const bf16x8*)(p_ + 4096);                               \
    dst[3] = *(const bf16x8*)(p_ + 6144);                               \
  } while (0)
#define READ_B(dst, bufi, ksb) do {                                     \
    const char* p_ = smem + (bufi) * BUF_BYTES + (ksb);                 \
    dst[0] = *(const bf16x8*)(p_);                                      \
    dst[1] = *(const bf16x8*)(p_ + 2048);                               \
  } while (0)

#define MFMA8(afs, bfs) do {                                            \
    __builtin_amdgcn_s_setprio(1);                                      \
    _Pragma("unroll")                                                   \
    for (int m_ = 0; m_ < 4; ++m_)                                      \
      _Pragma("unroll")                                                 \
      for (int n_ = 0; n_ < 2; ++n_)                                    \
        acc[m_][n_] = __builtin_amdgcn_mfma_f32_32x32x16_bf16(          \
            afs[m_], bfs[n_], acc[m_][n_], 0, 0, 0);                    \
    __builtin_amdgcn_s_setprio(0);                                      \
  } while (0)

#define VM(n) asm volatile("s_waitcnt vmcnt(" #n ")" ::: "memory")
#define BAR __builtin_amdgcn_s_barrier()

  // Phase A of tile tt (buf rb): read ks1 frags of tt, stage A(tt+3),
  // MFMA ks0, vmcnt(6)+barrier => tile tt+1 landed GLOBALLY.
#define PH_A(tt, rb, sb) do {                  \
    READ_A(afB, rb, base_a1);                  \
    READ_B(bfB, rb, base_b1);                  \
    STAGE_A((tt) + 3, sb);                     \
    MFMA8(afA, bfA);                           \
    VM(6); BAR;                                \
  } while (0)
  // Phase B of tile tt: read-ahead ks0 frags of tile tt+1 (landed),
  // stage B(tt+3), MFMA ks1, barrier.
#define PH_B(tt, rbn, sb) do {                 \
    READ_A(afA, rbn, base_a0);                 \
    READ_B(bfA, rbn, base_b0);                 \
    STAGE_B((tt) + 3, sb);                     \
    MFMA8(afB, bfB);                           \
    BAR;                                       \
  } while (0)

  // ---- prologue: stage tiles 0,1,2 (order pinned for vmcnt accounting)
  STAGE_A(0, 0); STAGE_B(0, 0);
  asm volatile("" ::: "memory");
  STAGE_A(1, 1); STAGE_B(1, 1);
  asm volatile("" ::: "memory");
  STAGE_A(2, 2); STAGE_B(2, 2);
  VM(8);  // tile 0 landed (own); barrier makes it global
  BAR;
  READ_A(afA, 0, base_a0);
  READ_B(bfA, 0, base_b0);

  // ---- main loop: tiles 0..123, stages 3..126 (4-tile unroll, static bufs)
#pragma unroll 1
  for (int tt = 0; tt < NT - 4; tt += 4) {
    PH_A(tt + 0, 0, 3); PH_B(tt + 0, 1, 3);
    PH_A(tt + 1, 1, 0); PH_B(tt + 1, 2, 0);
    PH_A(tt + 2, 2, 1); PH_B(tt + 2, 3, 1);
    PH_A(tt + 3, 3, 2); PH_B(tt + 3, 0, 2);
  }

  // ---- tail: tiles 124..127, drain 6 -> 4 -> 0
  // tile 124 (buf0), stages tile 127 -> buf3
  READ_A(afB, 0, base_a1); READ_B(bfB, 0, base_b1);
  STAGE_A(127, 3); MFMA8(afA, bfA); VM(6); BAR;
  READ_A(afA, 1, base_a0); READ_B(bfA, 1, base_b0);
  STAGE_B(127, 3); MFMA8(afB, bfB); BAR;
  // tile 125 (buf1): outstanding A(127)+B(127)=4 => tile 126 landed
  READ_A(afB, 1, base_a1); READ_B(bfB, 1, base_b1);
  MFMA8(afA, bfA); VM(4); BAR;
  READ_A(afA, 2, base_a0); READ_B(bfA, 2, base_b0);
  MFMA8(afB, bfB); BAR;
  // tile 126 (buf2): drain all => tile 127 landed
  READ_A(afB, 2, base_a1); READ_B(bfB, 2, base_b1);
  MFMA8(afA, bfA); VM(0); BAR;
  READ_A(afA, 3, base_a0); READ_B(bfA, 3, base_b0);
  MFMA8(afB, bfB); BAR;
  // tile 127 (buf3)
  READ_A(afB, 3, base_a1); READ_B(bfB, 3, base_b1);
  MFMA8(afA, bfA);
  MFMA8(afB, bfB);

  // ---- epilogue: 32x32 C/D layout col = lane&31, row = (reg&3)+8*(reg>>2)+4*kh
  const int orow_b = bm0 + wr * 128 + 4 * kh;
  const int ocol_b = bn0 + wc * 64 + l31;
  float bj[2];
  bj[0] = bias[ocol_b];
  bj[1] = bias[ocol_b + 32];
#pragma unroll
  for (int mi = 0; mi < 4; ++mi)
#pragma unroll
    for (int ni = 0; ni < 2; ++ni)
#pragma unroll
      for (int r = 0; r < 16; ++r) {
        const int row = orow_b + mi * 32 + (r & 3) + 8 * (r >> 2);
        out[(size_t)row * N_TOT + ocol_b + ni * 32] = acc[mi][ni][r] + bj[ni];
      }
}

extern "C" void kernel_launch(void* const* d_in, const int* in_sizes, int n_in,
                              void* d_out, int out_size, void* d_ws, size_t ws_size,
                              hipStream_t stream) {
  const float* x = (const float*)d_in[0];
  const int* widx = (const int*)d_in[1];
  const float* wsc = (const float*)d_in[2];
  const float* bias = (const float*)d_in[3];
  float* out = (float*)d_out;

  unsigned short* Abf = (unsigned short*)d_ws;                       // 64 MiB
  unsigned short* Wbf = (unsigned short*)((char*)d_ws + (size_t)M_TOT * K_TOT * 2);  // 32 MiB

  convert_x_kernel<<<dim3((M_TOT * (size_t)K_TOT / 8) / 256), dim3(256), 0, stream>>>(x, Abf);
  dequant_w_kernel<<<dim3((N_TOT * (size_t)K_TOT / 4) / 256), dim3(256), 0, stream>>>(widx, wsc, Wbf);

  (void)hipFuncSetAttribute((const void*)gemm256,
                            hipFuncAttributeMaxDynamicSharedMemorySize, LDS_BYTES);
  gemm256<<<dim3((M_TOT / BM) * (N_TOT / BN)), dim3(GTHREADS), LDS_BYTES, stream>>>(
      Abf, Wbf, bias, out);
}

// Round 6
// 282.157 us; speedup vs baseline: 1.0798x; 1.0755x over previous
//
#include <hip/hip_runtime.h>
#include <hip/hip_bf16.h>

static constexpr int M_TOT = 8192;   // 4 * 2048
static constexpr int N_TOT = 4096;   // OUT_F
static constexpr int K_TOT = 4096;   // IN_F

static constexpr int BM = 256, BN = 256;
static constexpr int GTHREADS = 512;            // 8 waves (2 M x 4 N)
static constexpr int LDS_BYTES = 131072;        // 2 dbuf x (A 32K + B 32K)

typedef __bf16 bf16x8 __attribute__((ext_vector_type(8)));
typedef float f32x4 __attribute__((ext_vector_type(4)));
typedef unsigned short u16x8 __attribute__((ext_vector_type(8)));

__device__ __forceinline__ unsigned short f2bf(float f) {
  return __builtin_bit_cast(unsigned short, (__bf16)f);
}

// FP4 E2M1 decode: mag 0..7 -> 0,0.5,1,1.5,2,3,4,6 ; bit 3 = sign
__device__ __forceinline__ float fp4_decode(int idx) {
  unsigned u = (unsigned)idx & 15u;
  unsigned sgn = (u >> 3) << 31;
  unsigned mag = u & 7u;
  unsigned e = mag >> 1, m = mag & 1u;
  unsigned bits = (e == 0u) ? (m ? 0x3F000000u : 0u)
                            : (((126u + e) << 23) | (m << 22));
  return __uint_as_float(bits | sgn);
}

__device__ __forceinline__ void glds16(const void* g, void* l) {
  __builtin_amdgcn_global_load_lds(
      (__attribute__((address_space(1))) void*)g,
      (__attribute__((address_space(3))) void*)l, 16, 0, 0);
}

// ---- prepass: weights int32 idx + scales -> bf16 W [N][K] -------------------
__global__ __launch_bounds__(256) void dequant_w_kernel(
    const int* __restrict__ idx, const float* __restrict__ scales,
    unsigned short* __restrict__ W) {
  const int t = blockIdx.x * 256 + threadIdx.x;  // 4 indices per thread
  const int4 v = reinterpret_cast<const int4*>(idx)[t];
  const float s = scales[t >> 2];
  ushort4 o;
  o.x = f2bf(fp4_decode(v.x) * s);
  o.y = f2bf(fp4_decode(v.y) * s);
  o.z = f2bf(fp4_decode(v.z) * s);
  o.w = f2bf(fp4_decode(v.w) * s);
  reinterpret_cast<ushort4*>(W)[t] = o;
}

// ---- prepass: x fp32 -> bf16 A [M][K] ---------------------------------------
__global__ __launch_bounds__(256) void convert_x_kernel(
    const float* __restrict__ x, unsigned short* __restrict__ A) {
  const int t = blockIdx.x * 256 + threadIdx.x;  // 8 floats per thread
  const float4* xp = reinterpret_cast<const float4*>(x);
  const float4 a = xp[2 * t], b = xp[2 * t + 1];
  u16x8 o;
  o[0] = f2bf(a.x); o[1] = f2bf(a.y); o[2] = f2bf(a.z); o[3] = f2bf(a.w);
  o[4] = f2bf(b.x); o[5] = f2bf(b.y); o[6] = f2bf(b.z); o[7] = f2bf(b.w);
  reinterpret_cast<u16x8*>(A)[t] = o;
}

// ---- GEMM: 256x256, 8-phase schedule (m201 port), 16x16x32 MFMA -------------
// LDS map per dbuf d (d0 @ 0 = even K-tiles, d1 @ 65536 = odd K-tiles):
//   As0 @ +0, As1 @ +16384, Bs0 @ +32768, Bs1 @ +49152  (each 16 KB)
// Sub-tile = [256 rows][32 k] bf16, 64 B rows, stored chunk = chunk ^ ((row>>1)&3)
// (R3's measured-zero-conflict layout). One sub staged per phase into the
// region whose last reader finished >=1 barrier earlier (rolling reuse).
__global__ __launch_bounds__(GTHREADS, 1) void gemm256(
    const unsigned short* __restrict__ A, const unsigned short* __restrict__ B,
    const float* __restrict__ bias, float* __restrict__ out) {
  extern __shared__ char smem[];

  const int t = threadIdx.x;
  const int lane = t & 63, wid = t >> 6;
  const int wr = wid >> 2;          // 0..1 (M half, 128 rows)
  const int wc = wid & 3;           // 0..3 (N quarter, 64 cols)
  const int l15 = lane & 15;

  // T1: XCD swizzle (512 blocks, 8 XCDs)
  const int bid = blockIdx.x;
  const int bmi = (bid & 7) * 4 + ((bid >> 3) & 3);  // 0..31
  const int bni = bid >> 5;                          // 0..15
  const int bm0 = bmi * BM, bn0 = bni * BN;

  // staging: linear LDS dest; source k-chunk pre-swizzled (c ^= (row>>1)&3)
  const int row_s = t >> 2;                   // 0..127
  const int kcd = (t & 3) ^ ((t >> 3) & 3);
  const unsigned short* pA = A + (size_t)(bm0 + row_s) * K_TOT + kcd * 8;
  const unsigned short* pB = B + (size_t)(bn0 + row_s) * K_TOT + kcd * 8;
  char* stA = smem + t * 16;           // + dbuf + s*16384 (+8192 rows 128-255)
  char* stB = smem + 32768 + t * 16;

  // ds_read side: same involution (frag rows = mult-of-16 + l15)
  const int swz = ((lane >> 4) ^ ((l15 >> 1) & 3)) * 16;
  const int base_a = (wr * 128 + l15) * 64 + swz;
  const int base_b = 32768 + (wc * 64 + l15) * 64 + swz;

  f32x4 acc[8][4];
#pragma unroll
  for (int i = 0; i < 8; ++i)
#pragma unroll
    for (int j = 0; j < 4; ++j) acc[i][j] = f32x4{0.f, 0.f, 0.f, 0.f};

  bf16x8 afQ[4], bfQ[4];

#define STG_A(T, s, doff) do {                                           \
    const unsigned short* p_ = pA + (T) * 64 + (s) * 32;                 \
    glds16(p_, stA + (doff) + (s) * 16384);                              \
    glds16(p_ + (size_t)128 * K_TOT, stA + (doff) + (s) * 16384 + 8192); \
  } while (0)
#define STG_B(T, s, doff) do {                                           \
    const unsigned short* p_ = pB + (T) * 64 + (s) * 32;                 \
    glds16(p_, stB + (doff) + (s) * 16384);                              \
    glds16(p_ + (size_t)128 * K_TOT, stB + (doff) + (s) * 16384 + 8192); \
  } while (0)

#define RD_A4(doff, s, mh) do {                                          \
    const char* p_ = smem + (doff) + (s) * 16384 + base_a + (mh) * 4096; \
    afQ[0] = *(const bf16x8*)(p_);                                       \
    afQ[1] = *(const bf16x8*)(p_ + 1024);                                \
    afQ[2] = *(const bf16x8*)(p_ + 2048);                                \
    afQ[3] = *(const bf16x8*)(p_ + 3072);                                \
  } while (0)
#define RD_B4(doff, s) do {                                              \
    const char* p_ = smem + (doff) + (s) * 16384 + base_b;               \
    bfQ[0] = *(const bf16x8*)(p_);                                       \
    bfQ[1] = *(const bf16x8*)(p_ + 1024);                                \
    bfQ[2] = *(const bf16x8*)(p_ + 2048);                                \
    bfQ[3] = *(const bf16x8*)(p_ + 3072);                                \
  } while (0)

#define MF16(mb) do {                                                    \
    __builtin_amdgcn_s_setprio(1);                                       \
    _Pragma("unroll")                                                    \
    for (int m_ = 0; m_ < 4; ++m_)                                       \
      _Pragma("unroll")                                                  \
      for (int n_ = 0; n_ < 4; ++n_)                                     \
        acc[(mb) + m_][n_] = __builtin_amdgcn_mfma_f32_16x16x32_bf16(    \
            afQ[m_], bfQ[n_], acc[(mb) + m_][n_], 0, 0, 0);              \
    __builtin_amdgcn_s_setprio(0);                                       \
  } while (0)

#define VM(n) asm volatile("s_waitcnt vmcnt(" #n ")" ::: "memory")
#define BAR __builtin_amdgcn_s_barrier()

  // ---- prologue: 7 subs (iter "-1" phases 1-7); gate + barrier
  STG_B(0, 0, 0);
  STG_A(0, 0, 0);
  STG_B(0, 1, 0);
  STG_A(0, 1, 0);
  STG_B(1, 0, 65536);
  STG_A(1, 0, 65536);
  STG_B(1, 1, 65536);
  VM(10);  // subs Bs0(T0), As0(T0) landed (own); BAR makes it global
  BAR;

  // ---- main loop: iters 0..30, tiles T=2i (d0) / U=2i+1 (d1)
  // Per phase: {reads ; stage 1 sub ; BAR ; MFMA quadrant ; VM(gate) ; BAR}
  // Gates: even-phase-end VM(12), odd-phase-end VM(10) (6/5 subs in flight).
#pragma unroll 1
  for (int i = 0; i < 31; ++i) {
    const int T = 2 * i, U = 2 * i + 1;
    // ph0: d0.s0 quadrant m0-3 ; stage d1.As1(U)
    RD_A4(0, 0, 0); RD_B4(0, 0); STG_A(U, 1, 65536);
    BAR; MF16(0); VM(12); BAR;
    // ph1: d0.s0 m4-7 ; stage d0.Bs0(T+2)
    RD_A4(0, 0, 1); STG_B(T + 2, 0, 0);
    BAR; MF16(4); VM(10); BAR;
    // ph2: d0.s1 m0-3 ; stage d0.As0(T+2)
    RD_A4(0, 1, 0); RD_B4(0, 1); STG_A(T + 2, 0, 0);
    BAR; MF16(0); VM(12); BAR;
    // ph3: d0.s1 m4-7 ; stage d0.Bs1(T+2)
    RD_A4(0, 1, 1); STG_B(T + 2, 1, 0);
    BAR; MF16(4); VM(10); BAR;
    // ph4: d1.s0 m0-3 ; stage d0.As1(T+2)
    RD_A4(65536, 0, 0); RD_B4(65536, 0); STG_A(T + 2, 1, 0);
    BAR; MF16(0); VM(12); BAR;
    // ph5: d1.s0 m4-7 ; stage d1.Bs0(U+2)
    RD_A4(65536, 0, 1); STG_B(U + 2, 0, 65536);
    BAR; MF16(4); VM(10); BAR;
    // ph6: d1.s1 m0-3 ; stage d1.As0(U+2)
    RD_A4(65536, 1, 0); RD_B4(65536, 1); STG_A(U + 2, 0, 65536);
    BAR; MF16(0); VM(12); BAR;
    // ph7: d1.s1 m4-7 ; stage d1.Bs1(U+2)
    RD_A4(65536, 1, 1); STG_B(U + 2, 1, 65536);
    BAR; MF16(4); VM(10); BAR;
  }

  // ---- final iter: tiles 62 (d0) / 63 (d1); only ph0 stages (A63s1); drain
  RD_A4(0, 0, 0); RD_B4(0, 0); STG_A(63, 1, 65536);
  BAR; MF16(0); VM(12); BAR;
  RD_A4(0, 0, 1);
  BAR; MF16(4); VM(8); BAR;
  RD_A4(0, 1, 0); RD_B4(0, 1);
  BAR; MF16(0); VM(8); BAR;
  RD_A4(0, 1, 1);
  BAR; MF16(4); VM(4); BAR;
  RD_A4(65536, 0, 0); RD_B4(65536, 0);
  BAR; MF16(0); VM(4); BAR;
  RD_A4(65536, 0, 1);
  BAR; MF16(4); VM(0); BAR;
  RD_A4(65536, 1, 0); RD_B4(65536, 1);
  BAR; MF16(0); BAR;
  RD_A4(65536, 1, 1);
  MF16(4);

  // ---- epilogue: C/D layout col = lane&15, row = (lane>>4)*4 + q
  const int orow0 = bm0 + wr * 128 + (lane >> 4) * 4;
  const int ocol0 = bn0 + wc * 64 + l15;
  float bj[4];
#pragma unroll
  for (int n = 0; n < 4; ++n) bj[n] = bias[ocol0 + n * 16];
#pragma unroll
  for (int mi = 0; mi < 8; ++mi)
#pragma unroll
    for (int n = 0; n < 4; ++n)
#pragma unroll
      for (int q = 0; q < 4; ++q)
        out[(size_t)(orow0 + mi * 16 + q) * N_TOT + ocol0 + n * 16] =
            acc[mi][n][q] + bj[n];
}

extern "C" void kernel_launch(void* const* d_in, const int* in_sizes, int n_in,
                              void* d_out, int out_size, void* d_ws, size_t ws_size,
                              hipStream_t stream) {
  const float* x = (const float*)d_in[0];
  const int* widx = (const int*)d_in[1];
  const float* wsc = (const float*)d_in[2];
  const float* bias = (const float*)d_in[3];
  float* out = (float*)d_out;

  unsigned short* Abf = (unsigned short*)d_ws;                       // 64 MiB
  unsigned short* Wbf = (unsigned short*)((char*)d_ws + (size_t)M_TOT * K_TOT * 2);  // 32 MiB

  convert_x_kernel<<<dim3((M_TOT * (size_t)K_TOT / 8) / 256), dim3(256), 0, stream>>>(x, Abf);
  dequant_w_kernel<<<dim3((N_TOT * (size_t)K_TOT / 4) / 256), dim3(256), 0, stream>>>(widx, wsc, Wbf);

  (void)hipFuncSetAttribute((const void*)gemm256,
                            hipFuncAttributeMaxDynamicSharedMemorySize, LDS_BYTES);
  gemm256<<<dim3((M_TOT / BM) * (N_TOT / BN)), dim3(GTHREADS), LDS_BYTES, stream>>>(
      Abf, Wbf, bias, out);
}